// Round 5
// baseline (151.388 us; speedup 1.0000x reference)
//
#include <hip/hip_runtime.h>
#include <math.h>

// B=4, T=4096, C=1024, H=64. fp32 in/out, bf16 MFMA internally.
// K1 wtrans: W (C,H) fp32 -> WT bf16 [192][1024].
// K2 qkv_proj: 256 thr, K-step 32, dbuf single-barrier LDS (31.5 KB -> 4+
//              blocks/CU). Each wave computes BOTH 16-row m-tiles reusing its
//              3 B-fragments: 5 ds_read_b128 per 6 MFMA (was 8/6).
// K3 attn: 128-row Q-tiles; each wave owns TWO q-groups (wv*16, 64+wv*16) and
//          reuses K-fragments (8 b128 -> 16 QK MFMA) and V-fragments (8 b128 ->
//          20 PV MFMA): LDS bytes/FLOP halved. kv-chunk = 4 tiles, 272 slots
//          per batch (base(i) = floor((i+1)^2/4)), grid 1088. Swapped mfma(K,Q),
//          in-register P transpose via cvt_pk_bf16 + permlane32/16_swap,
//          l=sum(p) via register-constant ones fragment. Plain-store partials
//          to private slab [slot][128][68].
// K4 reduce_norm: per row, sum ceil((i+1)/2) slabs, out = O_sum / l_sum.

#define BT   16384
#define TDIM 4096
#define CDIM 1024
#define HDIM 64
#define ACCW 68           // slab row stride (floats); col 64 holds l
#define NSLOT 272         // chunk slots per batch (chunk = 4 kv-tiles, q128)

typedef __attribute__((ext_vector_type(8))) short bf16x8;
typedef __attribute__((ext_vector_type(4))) float f32x4;
typedef __attribute__((ext_vector_type(8))) unsigned short us8;
typedef __attribute__((ext_vector_type(4))) unsigned short us4;

static __device__ __forceinline__ unsigned short f2bf(float f) {
    unsigned int u = __float_as_uint(f);
    u += 0x7fffu + ((u >> 16) & 1u);
    return (unsigned short)(u >> 16);
}

// Chained lane-swap: after pswap(x,y),
//   x = [X(q0), X(q2), Y(q0), Y(q2)] per quad, y = [X(q1), X(q3), Y(q1), Y(q3)]
// = A-frag words w / w+2 when X=c[st_lo][h], Y=c[st_hi][h].
static __device__ __forceinline__ void pswap(unsigned &x, unsigned &y) {
    asm("v_permlane32_swap_b32 %0, %1" : "+v"(x), "+v"(y));
    asm("v_permlane16_swap_b32 %0, %1" : "+v"(x), "+v"(y));
}

// ---------------- K1: W transpose->bf16 ----------------
__global__ __launch_bounds__(256) void wtrans(
    const float* __restrict__ Wk, const float* __restrict__ Wq,
    const float* __restrict__ Wv, unsigned short* __restrict__ wtg)
{
    int idx = blockIdx.x * 256 + threadIdx.x;     // 0..196607
    int mat = idx >> 16;
    int rem = idx & 65535;
    int h = rem >> 10, c = rem & 1023;
    const float* W = (mat == 0) ? Wk : (mat == 1) ? Wq : Wv;
    wtg[idx] = f2bf(W[c * HDIM + h]);             // WT[mat*64+h][c]
}

// ---------------- K2: QKV projection (K-step 32, 2 m-tiles/wave) ------------
__global__ __launch_bounds__(256, 4) void qkv_proj(
    const float* __restrict__ x, const unsigned short* __restrict__ wtg,
    unsigned short* __restrict__ kg, unsigned short* __restrict__ qg,
    unsigned short* __restrict__ vtg)
{
    __shared__ __align__(16) unsigned short xs[2][32][36];
    __shared__ __align__(16) unsigned short wts[2][192][36];   // 31.5 KB total
    const int t = threadIdx.x;
    const int lane = t & 63, wv = t >> 6, quad = lane >> 4, l16 = lane & 15;
    const int row0 = blockIdx.x * 32;

    const int xr = t >> 3, xc4 = (t & 7) * 4;     // x: 1 float4/thread/iter
    // WT: 3 us8/thread/iter at elements e = t, t+256, t+512
    const int wr0 = t >> 2,          wc0 = (t & 3) * 8;
    const int wr1 = (t + 256) >> 2,  wc1 = wc0;   // (t+256)&3 == t&3
    const int wr2 = (t + 512) >> 2,  wc2 = wc0;

    f32x4 acc[2][3];
    #pragma unroll
    for (int m = 0; m < 2; m++)
        #pragma unroll
        for (int j = 0; j < 3; j++) acc[m][j] = (f32x4){0.f, 0.f, 0.f, 0.f};

    const size_t xrow = (size_t)(row0 + xr) * CDIM + xc4;

    // prologue: tile 0 -> buf 0; preload tile 1 into regs
    float4 xv = *(const float4*)&x[xrow];
    us8 w0 = *(const us8*)&wtg[(size_t)wr0 * CDIM + wc0];
    us8 w1 = *(const us8*)&wtg[(size_t)wr1 * CDIM + wc1];
    us8 w2 = *(const us8*)&wtg[(size_t)wr2 * CDIM + wc2];
    {
        us4 pk = { f2bf(xv.x), f2bf(xv.y), f2bf(xv.z), f2bf(xv.w) };
        *(us4*)&xs[0][xr][xc4] = pk;
        *(us8*)&wts[0][wr0][wc0] = w0;
        *(us8*)&wts[0][wr1][wc1] = w1;
        *(us8*)&wts[0][wr2][wc2] = w2;
    }
    xv = *(const float4*)&x[xrow + 32];
    w0 = *(const us8*)&wtg[(size_t)wr0 * CDIM + 32 + wc0];
    w1 = *(const us8*)&wtg[(size_t)wr1 * CDIM + 32 + wc1];
    w2 = *(const us8*)&wtg[(size_t)wr2 * CDIM + 32 + wc2];
    __syncthreads();

    for (int it = 0; it < 32; it++) {
        const int buf = it & 1;
        if (it + 1 < 32) {
            us4 pk = { f2bf(xv.x), f2bf(xv.y), f2bf(xv.z), f2bf(xv.w) };
            *(us4*)&xs[buf ^ 1][xr][xc4] = pk;
            *(us8*)&wts[buf ^ 1][wr0][wc0] = w0;
            *(us8*)&wts[buf ^ 1][wr1][wc1] = w1;
            *(us8*)&wts[buf ^ 1][wr2][wc2] = w2;
            if (it + 2 < 32) {
                int nc = (it + 2) * 32;
                xv = *(const float4*)&x[xrow + nc];
                w0 = *(const us8*)&wtg[(size_t)wr0 * CDIM + nc + wc0];
                w1 = *(const us8*)&wtg[(size_t)wr1 * CDIM + nc + wc1];
                w2 = *(const us8*)&wtg[(size_t)wr2 * CDIM + nc + wc2];
            }
        }
        bf16x8 a0 = *(const bf16x8*)&xs[buf][l16][quad * 8];
        bf16x8 a1 = *(const bf16x8*)&xs[buf][16 + l16][quad * 8];
        #pragma unroll
        for (int j = 0; j < 3; j++) {
            int nt = wv * 3 + j;
            bf16x8 bb = *(const bf16x8*)&wts[buf][nt * 16 + l16][quad * 8];
            acc[0][j] = __builtin_amdgcn_mfma_f32_16x16x32_bf16(a0, bb, acc[0][j], 0, 0, 0);
            acc[1][j] = __builtin_amdgcn_mfma_f32_16x16x32_bf16(a1, bb, acc[1][j], 0, 0, 0);
        }
        __syncthreads();
    }

    #pragma unroll
    for (int mt = 0; mt < 2; mt++) {
        const int mrow = row0 + mt * 16 + quad * 4;
        #pragma unroll
        for (int j = 0; j < 3; j++) {
            int nt = wv * 3 + j;
            int mat = nt >> 2;
            int col = (nt & 3) * 16 + l16;
            if (mat == 2) {
                // V: 4 regs are 4 consecutive t at fixed h -> contiguous in vtg
                int bb = mrow >> 12, tr = mrow & 4095;  // rows never cross batch
                us4 pv = { f2bf(acc[mt][j][0]), f2bf(acc[mt][j][1]),
                           f2bf(acc[mt][j][2]), f2bf(acc[mt][j][3]) };
                *(us4*)&vtg[((size_t)(bb * HDIM + col) << 12) + tr] = pv;
            } else {
                // Q is pre-scaled by 1/8 (exact power-of-2 in bf16)
                float s = (mat == 1) ? 0.125f : 1.0f;
                unsigned short* dst = (mat == 0) ? kg : qg;
                #pragma unroll
                for (int reg = 0; reg < 4; reg++)
                    dst[(size_t)(mrow + reg) * HDIM + col] = f2bf(acc[mt][j][reg] * s);
            }
        }
    }
}

// ---------------- K3: flash attention, 128-row Q-tiles, 2 q-groups/wave -----
// slot decode: q128-tile i has nc = ceil((i+1)/2) chunks; base(i) = (i+1)^2/4.
__global__ __launch_bounds__(256, 3) void attn(
    const unsigned short* __restrict__ qg, const unsigned short* __restrict__ kg,
    const unsigned short* __restrict__ vtg, float* __restrict__ slabs)
{
    __shared__ __align__(16) unsigned short Ks[2][64][72];
    __shared__ __align__(16) unsigned short Vt[2][64][72];    // 36 KB total

    const int t = threadIdx.x;
    const int lane = t & 63, wv = t >> 6, quad = lane >> 4, l16 = lane & 15;

    const int b = blockIdx.x / NSLOT;
    const int s = blockIdx.x - b * NSLOT;
    int i = 0;
    while ((((i + 2) * (i + 2)) >> 2) <= s) ++i;          // <=31 SALU iters
    const int c = s - (((i + 1) * (i + 1)) >> 2);

    const size_t bbase = (size_t)b * TDIM;
    const int Q0 = i * 128;
    const int kt0 = c * 4;
    const int ktmax = 2 * i + 1;
    const int kt1 = (kt0 + 3 < ktmax) ? kt0 + 3 : ktmax;

    // Q fragments for both q-groups (B-operand of swapped QK^T)
    const int qr = Q0 + wv * 16 + l16;
    bf16x8 qa0[2], qa1[2];
    qa0[0] = *(const bf16x8*)&qg[(bbase + qr) * HDIM + quad * 8];
    qa1[0] = *(const bf16x8*)&qg[(bbase + qr) * HDIM + 32 + quad * 8];
    qa0[1] = *(const bf16x8*)&qg[(bbase + qr + 64) * HDIM + quad * 8];
    qa1[1] = *(const bf16x8*)&qg[(bbase + qr + 64) * HDIM + 32 + quad * 8];

    // l-row B-fragment: register constant
    const short onev = (l16 == 0) ? (short)0x3F80 : (short)0;
    const bf16x8 ones = { onev, onev, onev, onev, onev, onev, onev, onev };

    f32x4 O[2][5];
    #pragma unroll
    for (int g = 0; g < 2; g++)
        #pragma unroll
        for (int n = 0; n < 5; n++) O[g][n] = (f32x4){0.f, 0.f, 0.f, 0.f};

    const int fr = t >> 3, fc = (t & 7) * 8;

    // prologue: tile kt0 -> buf 0; preload tile kt0+1 into regs
    us8 kr0 = *(const us8*)&kg[(bbase + kt0 * 64 + fr) * HDIM + fc];
    us8 kr1 = *(const us8*)&kg[(bbase + kt0 * 64 + fr + 32) * HDIM + fc];
    us8 vr0 = *(const us8*)&vtg[((size_t)(b * HDIM + fr) << 12) + kt0 * 64 + fc];
    us8 vr1 = *(const us8*)&vtg[((size_t)(b * HDIM + fr + 32) << 12) + kt0 * 64 + fc];
    *(us8*)&Ks[0][fr][fc] = kr0;
    *(us8*)&Ks[0][fr + 32][fc] = kr1;
    *(us8*)&Vt[0][fr][fc] = vr0;
    *(us8*)&Vt[0][fr + 32][fc] = vr1;
    if (kt0 < kt1) {
        int kn = kt0 + 1;
        kr0 = *(const us8*)&kg[(bbase + kn * 64 + fr) * HDIM + fc];
        kr1 = *(const us8*)&kg[(bbase + kn * 64 + fr + 32) * HDIM + fc];
        vr0 = *(const us8*)&vtg[((size_t)(b * HDIM + fr) << 12) + kn * 64 + fc];
        vr1 = *(const us8*)&vtg[((size_t)(b * HDIM + fr + 32) << 12) + kn * 64 + fc];
    }
    __syncthreads();

    const int qloc = wv * 16 + l16;
    int buf = 0;
    for (int kt = kt0; kt <= kt1; kt++) {
        const int d = kt - 2 * i;      // <0 plain; 0: g0 diag; 1: g0 skip, g1 diag
        const bool do0 = (d < 1);

        // shared K fragments (read once, used by both q-groups)
        bf16x8 kb0[4], kb1[4];
        #pragma unroll
        for (int st = 0; st < 4; st++) {
            kb0[st] = *(const bf16x8*)&Ks[buf][st * 16 + l16][quad * 8];
            kb1[st] = *(const bf16x8*)&Ks[buf][st * 16 + l16][32 + quad * 8];
        }

        // stage tile kt+1 into buf^1, overlapped with compute
        if (kt < kt1) {
            *(us8*)&Ks[buf ^ 1][fr][fc] = kr0;
            *(us8*)&Ks[buf ^ 1][fr + 32][fc] = kr1;
            *(us8*)&Vt[buf ^ 1][fr][fc] = vr0;
            *(us8*)&Vt[buf ^ 1][fr + 32][fc] = vr1;
            if (kt + 1 < kt1) {
                int kn = kt + 2;
                kr0 = *(const us8*)&kg[(bbase + kn * 64 + fr) * HDIM + fc];
                kr1 = *(const us8*)&kg[(bbase + kn * 64 + fr + 32) * HDIM + fc];
                vr0 = *(const us8*)&vtg[((size_t)(b * HDIM + fr) << 12) + kn * 64 + fc];
                vr1 = *(const us8*)&vtg[((size_t)(b * HDIM + fr + 32) << 12) + kn * 64 + fc];
            }
        }

        bf16x8 pa0[2], pa1[2];
        #pragma unroll
        for (int g = 0; g < 2; g++) {
            if (g == 0 && !do0) continue;
            // S^T for this q-group
            f32x4 sT[4];
            #pragma unroll
            for (int st = 0; st < 4; st++) {
                f32x4 z = (f32x4){0.f, 0.f, 0.f, 0.f};
                z = __builtin_amdgcn_mfma_f32_16x16x32_bf16(kb0[st], qa0[g], z, 0, 0, 0);
                z = __builtin_amdgcn_mfma_f32_16x16x32_bf16(kb1[st], qa1[g], z, 0, 0, 0);
                sT[st] = z;
            }
            // p = exp(s); diagonal mask when this group is the diagonal one
            const bool diag = (d == g);      // d==0&&g==0 or d==1&&g==1
            float p[4][4];
            if (diag) {
                #pragma unroll
                for (int st = 0; st < 4; st++)
                    #pragma unroll
                    for (int r = 0; r < 4; r++) {
                        int kkloc = st * 16 + quad * 4 + r;
                        p[st][r] = (kkloc > qloc) ? 0.f : __expf(sT[st][r]);
                    }
            } else {
                #pragma unroll
                for (int st = 0; st < 4; st++)
                    #pragma unroll
                    for (int r = 0; r < 4; r++)
                        p[st][r] = __expf(sT[st][r]);
            }
            // pack + permlane into PV A-fragment layout
            unsigned cpk[4][2];
            #pragma unroll
            for (int st = 0; st < 4; st++) {
                asm("v_cvt_pk_bf16_f32 %0, %1, %2"
                    : "=v"(cpk[st][0]) : "v"(p[st][0]), "v"(p[st][1]));
                asm("v_cvt_pk_bf16_f32 %0, %1, %2"
                    : "=v"(cpk[st][1]) : "v"(p[st][2]), "v"(p[st][3]));
            }
            union { unsigned u[4]; bf16x8 v; } u0, u1;
            unsigned a0 = cpk[0][0], b0 = cpk[1][0]; pswap(a0, b0);
            unsigned a1 = cpk[0][1], b1 = cpk[1][1]; pswap(a1, b1);
            u0.u[0] = a0; u0.u[1] = a1; u0.u[2] = b0; u0.u[3] = b1;
            unsigned a2 = cpk[2][0], b2 = cpk[3][0]; pswap(a2, b2);
            unsigned a3 = cpk[2][1], b3 = cpk[3][1]; pswap(a3, b3);
            u1.u[0] = a2; u1.u[1] = a3; u1.u[2] = b2; u1.u[3] = b3;
            pa0[g] = u0.v; pa1[g] = u1.v;
        }

        // O += P V: V fragments read once (transient), used by both groups
        #pragma unroll
        for (int nt = 0; nt < 4; nt++) {
            bf16x8 vb0 = *(const bf16x8*)&Vt[buf][nt * 16 + l16][quad * 8];
            bf16x8 vb1 = *(const bf16x8*)&Vt[buf][nt * 16 + l16][32 + quad * 8];
            if (do0) {
                O[0][nt] = __builtin_amdgcn_mfma_f32_16x16x32_bf16(pa0[0], vb0, O[0][nt], 0, 0, 0);
                O[0][nt] = __builtin_amdgcn_mfma_f32_16x16x32_bf16(pa1[0], vb1, O[0][nt], 0, 0, 0);
            }
            O[1][nt] = __builtin_amdgcn_mfma_f32_16x16x32_bf16(pa0[1], vb0, O[1][nt], 0, 0, 0);
            O[1][nt] = __builtin_amdgcn_mfma_f32_16x16x32_bf16(pa1[1], vb1, O[1][nt], 0, 0, 0);
        }
        if (do0) {
            O[0][4] = __builtin_amdgcn_mfma_f32_16x16x32_bf16(pa0[0], ones, O[0][4], 0, 0, 0);
            O[0][4] = __builtin_amdgcn_mfma_f32_16x16x32_bf16(pa1[0], ones, O[0][4], 0, 0, 0);
        }
        O[1][4] = __builtin_amdgcn_mfma_f32_16x16x32_bf16(pa0[1], ones, O[1][4], 0, 0, 0);
        O[1][4] = __builtin_amdgcn_mfma_f32_16x16x32_bf16(pa1[1], ones, O[1][4], 0, 0, 0);

        __syncthreads();
        buf ^= 1;
    }

    // flush partials to this block's private slab slot (plain stores)
    float* slab = slabs + (size_t)(b * NSLOT + s) * 128 * ACCW;
    #pragma unroll
    for (int g = 0; g < 2; g++) {
        const int rl = g * 64 + wv * 16 + quad * 4;
        #pragma unroll
        for (int nt = 0; nt < 4; nt++)
            #pragma unroll
            for (int r = 0; r < 4; r++)
                slab[(size_t)(rl + r) * ACCW + nt * 16 + l16] = O[g][nt][r];
        if (l16 == 0) {
            #pragma unroll
            for (int r = 0; r < 4; r++)
                slab[(size_t)(rl + r) * ACCW + 64] = O[g][4][r];
        }
    }
}

// ---------------- K4: reduce slabs + normalize ----------------
__global__ __launch_bounds__(256) void reduce_norm(
    const float* __restrict__ slabs, float* __restrict__ out)
{
    int idx = blockIdx.x * 256 + threadIdx.x;   // 262144 = 16384 rows * 16 float4
    int row = idx >> 4, c4 = (idx & 15) * 4;
    int b = row >> 12, i = (row >> 7) & 31, r128 = row & 127;
    int nc = (i + 2) >> 1;                       // ceil((i+1)/2)
    int base = ((i + 1) * (i + 1)) >> 2;         // first slot of tile i

    const float* sl = slabs + ((size_t)(b * NSLOT + base) * 128 + r128) * ACCW;
    float4 o = make_float4(0.f, 0.f, 0.f, 0.f);
    float l = 0.f;
    for (int k = 0; k < nc; k++) {
        float4 v = *(const float4*)&sl[c4];
        o.x += v.x; o.y += v.y; o.z += v.z; o.w += v.w;
        l += sl[64];
        sl += (size_t)128 * ACCW;
    }
    float inv = 1.f / l;
    *(float4*)&out[(size_t)row * HDIM + c4] =
        make_float4(o.x * inv, o.y * inv, o.z * inv, o.w * inv);
}

extern "C" void kernel_launch(void* const* d_in, const int* in_sizes, int n_in,
                              void* d_out, int out_size, void* d_ws, size_t ws_size,
                              hipStream_t stream) {
    const float* x  = (const float*)d_in[0];
    const float* Wk = (const float*)d_in[1];
    const float* Wq = (const float*)d_in[2];
    const float* Wv = (const float*)d_in[3];
    float* out = (float*)d_out;

    unsigned short* wtg = (unsigned short*)d_ws;        // [192][1024] bf16
    unsigned short* kg  = wtg + 196608;                 // [BT][64] bf16
    unsigned short* qg  = kg + (size_t)BT * HDIM;       // [BT][64] bf16 (q/8)
    unsigned short* vtg = qg + (size_t)BT * HDIM;       // [4][64][4096] bf16
    float* slabs = (float*)(vtg + (size_t)4 * HDIM * TDIM); // [4*272][128][68]

    wtrans<<<768, 256, 0, stream>>>(Wk, Wq, Wv, wtg);
    qkv_proj<<<BT / 32, 256, 0, stream>>>(x, wtg, kg, qg, vtg);
    attn<<<4 * NSLOT, 256, 0, stream>>>(qg, kg, vtg, slabs);
    reduce_norm<<<BT * HDIM / (4 * 256), 256, 0, stream>>>(slabs, out);
}

// Round 6
// 141.673 us; speedup vs baseline: 1.0686x; 1.0686x over previous
//
#include <hip/hip_runtime.h>
#include <math.h>

// B=4, T=4096, C=1024, H=64. fp32 in/out, bf16 MFMA internally.
// K1 wtrans: W (C,H) fp32 -> WT bf16 [192][1024].
// K2 qkv_proj: 512 thr, K-step 64, [72]-short LDS rows (0 bank conflicts),
//              single-barrier dbuf. x prefetched via 8-deep register ring
//              (~2400 cyc lookahead >> 900 cyc HBM latency); WT 1-iter ahead.
//              k bf16 [BT][64]; q pre-scaled by 1/8; v transposed, packed us4.
// K3 attn: r4 structure (chunk=8 kv-tiles, NSLOT=288, 36KB LDS dbuf, 4 blk/CU)
//          + s_setprio(1) around QK and PV MFMA clusters (T5). Swapped
//          mfma(K,Q); in-register P transpose via cvt_pk_bf16 + permlane
//          swaps; l=sum(p) via register-constant ones fragment; plain-store
//          partials to private slab [slot][64][68].
// K4 reduce_norm: per row, sum ceil((qt+1)/8) slabs, out = O_sum / l_sum.

#define BT   16384
#define TDIM 4096
#define CDIM 1024
#define HDIM 64
#define ACCW 68           // slab row stride (floats); col 64 holds l
#define NSLOT 288         // chunk slots per batch (chunk = 8 kv-tiles)

typedef __attribute__((ext_vector_type(8))) short bf16x8;
typedef __attribute__((ext_vector_type(4))) float f32x4;
typedef __attribute__((ext_vector_type(8))) unsigned short us8;
typedef __attribute__((ext_vector_type(4))) unsigned short us4;

static __device__ __forceinline__ unsigned short f2bf(float f) {
    unsigned int u = __float_as_uint(f);
    u += 0x7fffu + ((u >> 16) & 1u);
    return (unsigned short)(u >> 16);
}

// Chained lane-swap: after pswap(x,y),
//   x = [X(q0), X(q2), Y(q0), Y(q2)] per quad, y = [X(q1), X(q3), Y(q1), Y(q3)]
// = A-frag words w / w+2 when X=c[st_lo][h], Y=c[st_hi][h].
static __device__ __forceinline__ void pswap(unsigned &x, unsigned &y) {
    asm("v_permlane32_swap_b32 %0, %1" : "+v"(x), "+v"(y));
    asm("v_permlane16_swap_b32 %0, %1" : "+v"(x), "+v"(y));
}

// ---------------- K1: W transpose->bf16 ----------------
__global__ __launch_bounds__(256) void wtrans(
    const float* __restrict__ Wk, const float* __restrict__ Wq,
    const float* __restrict__ Wv, unsigned short* __restrict__ wtg)
{
    int idx = blockIdx.x * 256 + threadIdx.x;     // 0..196607
    int mat = idx >> 16;
    int rem = idx & 65535;
    int h = rem >> 10, c = rem & 1023;
    const float* W = (mat == 0) ? Wk : (mat == 1) ? Wq : Wv;
    wtg[idx] = f2bf(W[c * HDIM + h]);             // WT[mat*64+h][c]
}

// ---------------- K2: QKV projection (8-deep x-ring, single-barrier dbuf) ---
__global__ __launch_bounds__(512) void qkv_proj(
    const float* __restrict__ x, const unsigned short* __restrict__ wtg,
    unsigned short* __restrict__ kg, unsigned short* __restrict__ qg,
    unsigned short* __restrict__ vtg)
{
    __shared__ __align__(16) unsigned short xs[2][32][72];
    __shared__ __align__(16) unsigned short wts[2][192][72];   // total 63 KB
    const int t = threadIdx.x;
    const int lane = t & 63, wv = t >> 6, quad = lane >> 4, l16 = lane & 15;
    const int mt = wv >> 2;                  // m-tile 0/1 (16 rows each)
    const int nq = wv & 3;                   // n-quarter: n-tiles nq*3..nq*3+2
    const int row0 = blockIdx.x * 32;

    const int xr = t >> 4, xc4 = (t & 15) * 4;       // x: 1 float4/thread/iter
    const int wn = t >> 3, wc8 = (t & 7) * 8;        // WT: 3 us8/thread/iter

    f32x4 acc3[3];
    #pragma unroll
    for (int i = 0; i < 3; i++) acc3[i] = (f32x4){0.f, 0.f, 0.f, 0.f};

    const size_t xrow = (size_t)(row0 + xr) * CDIM + xc4;

    // deep prefetch: issue 8 x-chunk loads up front (static-indexed ring)
    float4 xq[8];
    #pragma unroll
    for (int c = 0; c < 8; c++)
        xq[c] = *(const float4*)&x[xrow + c * 64];

    // WT chunk 0 regs
    us8 w0 = *(const us8*)&wtg[(size_t)(wn +   0) * CDIM + wc8];
    us8 w1 = *(const us8*)&wtg[(size_t)(wn +  64) * CDIM + wc8];
    us8 w2 = *(const us8*)&wtg[(size_t)(wn + 128) * CDIM + wc8];

    // stage tile 0 -> buf 0 (consumes xq[0]); refill slot 0 with chunk 8
    {
        us4 pk = { f2bf(xq[0].x), f2bf(xq[0].y), f2bf(xq[0].z), f2bf(xq[0].w) };
        *(us4*)&xs[0][xr][xc4] = pk;
        *(us8*)&wts[0][wn +   0][wc8] = w0;
        *(us8*)&wts[0][wn +  64][wc8] = w1;
        *(us8*)&wts[0][wn + 128][wc8] = w2;
    }
    xq[0] = *(const float4*)&x[xrow + 8 * 64];
    w0 = *(const us8*)&wtg[(size_t)(wn +   0) * CDIM + 64 + wc8];
    w1 = *(const us8*)&wtg[(size_t)(wn +  64) * CDIM + 64 + wc8];
    w2 = *(const us8*)&wtg[(size_t)(wn + 128) * CDIM + 64 + wc8];
    __syncthreads();

    #pragma unroll
    for (int it = 0; it < 16; it++) {
        const int buf = it & 1;
        if (it + 1 < 16) {
            // stage tile it+1 from ring slot (it+1)&7 and WT regs
            const int sl = (it + 1) & 7;
            us4 pk = { f2bf(xq[sl].x), f2bf(xq[sl].y),
                       f2bf(xq[sl].z), f2bf(xq[sl].w) };
            *(us4*)&xs[buf ^ 1][xr][xc4] = pk;
            *(us8*)&wts[buf ^ 1][wn +   0][wc8] = w0;
            *(us8*)&wts[buf ^ 1][wn +  64][wc8] = w1;
            *(us8*)&wts[buf ^ 1][wn + 128][wc8] = w2;
            if (it + 9 < 16)
                xq[sl] = *(const float4*)&x[xrow + (it + 9) * 64];
            if (it + 2 < 16) {
                int nc = (it + 2) * 64;
                w0 = *(const us8*)&wtg[(size_t)(wn +   0) * CDIM + nc + wc8];
                w1 = *(const us8*)&wtg[(size_t)(wn +  64) * CDIM + nc + wc8];
                w2 = *(const us8*)&wtg[(size_t)(wn + 128) * CDIM + nc + wc8];
            }
        }
        bf16x8 a0 = *(const bf16x8*)&xs[buf][mt * 16 + l16][quad * 8];
        bf16x8 a1 = *(const bf16x8*)&xs[buf][mt * 16 + l16][32 + quad * 8];
        #pragma unroll
        for (int j = 0; j < 3; j++) {
            int nt = nq * 3 + j;
            bf16x8 b0 = *(const bf16x8*)&wts[buf][nt * 16 + l16][quad * 8];
            bf16x8 b1 = *(const bf16x8*)&wts[buf][nt * 16 + l16][32 + quad * 8];
            acc3[j] = __builtin_amdgcn_mfma_f32_16x16x32_bf16(a0, b0, acc3[j], 0, 0, 0);
            acc3[j] = __builtin_amdgcn_mfma_f32_16x16x32_bf16(a1, b1, acc3[j], 0, 0, 0);
        }
        __syncthreads();
    }

    const int mrow = row0 + mt * 16 + quad * 4;
    #pragma unroll
    for (int j = 0; j < 3; j++) {
        int nt = nq * 3 + j;
        int mat = nt >> 2;
        int col = (nt & 3) * 16 + l16;
        if (mat == 2) {
            // V: 4 regs are 4 consecutive t at fixed h -> contiguous in vtg
            int bb = mrow >> 12, tr = mrow & 4095;   // rows never cross batch
            us4 pv = { f2bf(acc3[j][0]), f2bf(acc3[j][1]),
                       f2bf(acc3[j][2]), f2bf(acc3[j][3]) };
            *(us4*)&vtg[((size_t)(bb * HDIM + col) << 12) + tr] = pv;
        } else {
            // Q is pre-scaled by 1/8 (exact power-of-2 in bf16)
            float s = (mat == 1) ? 0.125f : 1.0f;
            unsigned short* dst = (mat == 0) ? kg : qg;
            #pragma unroll
            for (int reg = 0; reg < 4; reg++)
                dst[(size_t)(mrow + reg) * HDIM + col] = f2bf(acc3[j][reg] * s);
        }
    }
}

// ---------------- K3: chunked flash attention, slab outputs ----------
// slot layout per batch (chunk = 8 tiles): group a = qt>>3 has (a+1) chunks
// per qt; group a starts at slot 4a(a+1); qt's slots: base + (qt&7)*(a+1).
__global__ __launch_bounds__(256) void attn(
    const unsigned short* __restrict__ qg, const unsigned short* __restrict__ kg,
    const unsigned short* __restrict__ vtg, float* __restrict__ slabs)
{
    __shared__ __align__(16) unsigned short Ks[2][64][72];
    __shared__ __align__(16) unsigned short Vt[2][64][72];    // 36 KB total

    const int t = threadIdx.x;
    const int lane = t & 63, wv = t >> 6, quad = lane >> 4, l16 = lane & 15;

    const int b = blockIdx.x / NSLOT;
    const int s = blockIdx.x - b * NSLOT;
    int a;
    if      (s < 8)   a = 0;
    else if (s < 24)  a = 1;
    else if (s < 48)  a = 2;
    else if (s < 80)  a = 3;
    else if (s < 120) a = 4;
    else if (s < 168) a = 5;
    else if (s < 224) a = 6;
    else              a = 7;
    const int u  = s - 4 * a * (a + 1);
    const int qt = a * 8 + u / (a + 1);
    const int c  = u % (a + 1);

    const size_t bbase = (size_t)b * TDIM;
    const int Q0 = qt * 64;
    const int kt0 = c * 8;
    const int kt1 = (kt0 + 7 < qt) ? kt0 + 7 : qt;

    // Q fragments (B-operand of swapped QK^T: n=l16 is the q-row)
    const int qrow = Q0 + wv * 16 + l16;
    const bf16x8 qa0 = *(const bf16x8*)&qg[(bbase + qrow) * HDIM + quad * 8];
    const bf16x8 qa1 = *(const bf16x8*)&qg[(bbase + qrow) * HDIM + 32 + quad * 8];

    // l-row B-fragment: register constant (col 0 of virtual ones-row)
    const short onev = (l16 == 0) ? (short)0x3F80 : (short)0;
    const bf16x8 ones = { onev, onev, onev, onev, onev, onev, onev, onev };

    f32x4 O[5];
    #pragma unroll
    for (int i = 0; i < 5; i++) O[i] = (f32x4){0.f, 0.f, 0.f, 0.f};

    const int fr = t >> 3, fc = (t & 7) * 8;

    // prologue: tile kt0 -> buf 0; preload tile kt0+1 into regs
    us8 kr0 = *(const us8*)&kg[(bbase + kt0 * 64 + fr) * HDIM + fc];
    us8 kr1 = *(const us8*)&kg[(bbase + kt0 * 64 + fr + 32) * HDIM + fc];
    us8 vr0 = *(const us8*)&vtg[((size_t)(b * HDIM + fr) << 12) + kt0 * 64 + fc];
    us8 vr1 = *(const us8*)&vtg[((size_t)(b * HDIM + fr + 32) << 12) + kt0 * 64 + fc];
    *(us8*)&Ks[0][fr][fc] = kr0;
    *(us8*)&Ks[0][fr + 32][fc] = kr1;
    *(us8*)&Vt[0][fr][fc] = vr0;
    *(us8*)&Vt[0][fr + 32][fc] = vr1;
    if (kt0 < kt1) {
        int kn = kt0 + 1;
        kr0 = *(const us8*)&kg[(bbase + kn * 64 + fr) * HDIM + fc];
        kr1 = *(const us8*)&kg[(bbase + kn * 64 + fr + 32) * HDIM + fc];
        vr0 = *(const us8*)&vtg[((size_t)(b * HDIM + fr) << 12) + kn * 64 + fc];
        vr1 = *(const us8*)&vtg[((size_t)(b * HDIM + fr + 32) << 12) + kn * 64 + fc];
    }
    __syncthreads();

    const int qloc = wv * 16 + l16;        // this lane's q row, Q-tile-local
    int buf = 0;
    for (int kt = kt0; kt <= kt1; kt++) {
        // S^T = K Q^T from Ks[buf] (prioritized MFMA cluster)
        __builtin_amdgcn_s_setprio(1);
        f32x4 sT[4];
        #pragma unroll
        for (int st = 0; st < 4; st++) {
            bf16x8 kb0 = *(const bf16x8*)&Ks[buf][st * 16 + l16][quad * 8];
            bf16x8 kb1 = *(const bf16x8*)&Ks[buf][st * 16 + l16][32 + quad * 8];
            f32x4 z = (f32x4){0.f, 0.f, 0.f, 0.f};
            z = __builtin_amdgcn_mfma_f32_16x16x32_bf16(kb0, qa0, z, 0, 0, 0);
            z = __builtin_amdgcn_mfma_f32_16x16x32_bf16(kb1, qa1, z, 0, 0, 0);
            sT[st] = z;
        }
        __builtin_amdgcn_s_setprio(0);

        // stage tile kt+1 (in regs) into buf^1, overlapped with exp/pack/PV
        if (kt < kt1) {
            *(us8*)&Ks[buf ^ 1][fr][fc] = kr0;
            *(us8*)&Ks[buf ^ 1][fr + 32][fc] = kr1;
            *(us8*)&Vt[buf ^ 1][fr][fc] = vr0;
            *(us8*)&Vt[buf ^ 1][fr + 32][fc] = vr1;
            if (kt + 1 < kt1) {
                int kn = kt + 2;
                kr0 = *(const us8*)&kg[(bbase + kn * 64 + fr) * HDIM + fc];
                kr1 = *(const us8*)&kg[(bbase + kn * 64 + fr + 32) * HDIM + fc];
                vr0 = *(const us8*)&vtg[((size_t)(b * HDIM + fr) << 12) + kn * 64 + fc];
                vr1 = *(const us8*)&vtg[((size_t)(b * HDIM + fr + 32) << 12) + kn * 64 + fc];
            }
        }

        // p = exp(s) (q pre-scaled by 1/8); causal mask only on diagonal tile
        float p[4][4];
        if (kt == qt) {
            #pragma unroll
            for (int st = 0; st < 4; st++)
                #pragma unroll
                for (int r = 0; r < 4; r++) {
                    int kkloc = st * 16 + quad * 4 + r;
                    p[st][r] = (kkloc > qloc) ? 0.f : __expf(sT[st][r]);
                }
        } else {
            #pragma unroll
            for (int st = 0; st < 4; st++)
                #pragma unroll
                for (int r = 0; r < 4; r++)
                    p[st][r] = __expf(sT[st][r]);
        }

        // pack pairs to bf16, then permlane-swap into PV A-fragment layout
        unsigned cpk[4][2];
        #pragma unroll
        for (int st = 0; st < 4; st++) {
            asm("v_cvt_pk_bf16_f32 %0, %1, %2"
                : "=v"(cpk[st][0]) : "v"(p[st][0]), "v"(p[st][1]));
            asm("v_cvt_pk_bf16_f32 %0, %1, %2"
                : "=v"(cpk[st][1]) : "v"(p[st][2]), "v"(p[st][3]));
        }
        union { unsigned u[4]; bf16x8 v; } pa0u, pa1u;
        {
            unsigned a0 = cpk[0][0], b0 = cpk[1][0]; pswap(a0, b0);
            unsigned a1 = cpk[0][1], b1 = cpk[1][1]; pswap(a1, b1);
            pa0u.u[0] = a0; pa0u.u[1] = a1; pa0u.u[2] = b0; pa0u.u[3] = b1;
            unsigned a2 = cpk[2][0], b2 = cpk[3][0]; pswap(a2, b2);
            unsigned a3 = cpk[2][1], b3 = cpk[3][1]; pswap(a3, b3);
            pa1u.u[0] = a2; pa1u.u[1] = a3; pa1u.u[2] = b2; pa1u.u[3] = b3;
        }
        const bf16x8 pa0 = pa0u.v, pa1 = pa1u.v;

        // O += P V from Vt[buf] (prioritized MFMA cluster)
        __builtin_amdgcn_s_setprio(1);
        #pragma unroll
        for (int nt = 0; nt < 4; nt++) {
            bf16x8 vb0 = *(const bf16x8*)&Vt[buf][nt * 16 + l16][quad * 8];
            bf16x8 vb1 = *(const bf16x8*)&Vt[buf][nt * 16 + l16][32 + quad * 8];
            O[nt] = __builtin_amdgcn_mfma_f32_16x16x32_bf16(pa0, vb0, O[nt], 0, 0, 0);
            O[nt] = __builtin_amdgcn_mfma_f32_16x16x32_bf16(pa1, vb1, O[nt], 0, 0, 0);
        }
        O[4] = __builtin_amdgcn_mfma_f32_16x16x32_bf16(pa0, ones, O[4], 0, 0, 0);
        O[4] = __builtin_amdgcn_mfma_f32_16x16x32_bf16(pa1, ones, O[4], 0, 0, 0);
        __builtin_amdgcn_s_setprio(0);

        __syncthreads();
        buf ^= 1;
    }

    // flush partials to this block's private slab slot (plain stores)
    float* slab = slabs + (size_t)(b * NSLOT + s) * 64 * ACCW;
    const int rl = wv * 16 + quad * 4;
    #pragma unroll
    for (int nt = 0; nt < 4; nt++)
        #pragma unroll
        for (int r = 0; r < 4; r++)
            slab[(size_t)(rl + r) * ACCW + nt * 16 + l16] = O[nt][r];
    if (l16 == 0) {
        #pragma unroll
        for (int r = 0; r < 4; r++)
            slab[(size_t)(rl + r) * ACCW + 64] = O[4][r];
    }
}

// ---------------- K4: reduce slabs + normalize ----------------
__global__ __launch_bounds__(256) void reduce_norm(
    const float* __restrict__ slabs, float* __restrict__ out)
{
    int idx = blockIdx.x * 256 + threadIdx.x;   // 262144 = 16384 rows * 16 float4
    int row = idx >> 4, c4 = (idx & 15) * 4;
    int b = row >> 12, qt = (row >> 6) & 63, r64 = row & 63;
    int a = qt >> 3, nc = a + 1;
    int base = 4 * a * (a + 1) + (qt & 7) * nc;    // first slot of this qt

    const float* sl = slabs + ((size_t)(b * NSLOT + base) * 64 + r64) * ACCW;
    float4 o = make_float4(0.f, 0.f, 0.f, 0.f);
    float l = 0.f;
    for (int i = 0; i < nc; i++) {
        float4 v = *(const float4*)&sl[c4];
        o.x += v.x; o.y += v.y; o.z += v.z; o.w += v.w;
        l += sl[64];
        sl += (size_t)64 * ACCW;
    }
    float inv = 1.f / l;
    *(float4*)&out[(size_t)row * HDIM + c4] =
        make_float4(o.x * inv, o.y * inv, o.z * inv, o.w * inv);
}

extern "C" void kernel_launch(void* const* d_in, const int* in_sizes, int n_in,
                              void* d_out, int out_size, void* d_ws, size_t ws_size,
                              hipStream_t stream) {
    const float* x  = (const float*)d_in[0];
    const float* Wk = (const float*)d_in[1];
    const float* Wq = (const float*)d_in[2];
    const float* Wv = (const float*)d_in[3];
    float* out = (float*)d_out;

    unsigned short* wtg = (unsigned short*)d_ws;        // [192][1024] bf16
    unsigned short* kg  = wtg + 196608;                 // [BT][64] bf16
    unsigned short* qg  = kg + (size_t)BT * HDIM;       // [BT][64] bf16 (q/8)
    unsigned short* vtg = qg + (size_t)BT * HDIM;       // [4][64][4096] bf16
    float* slabs = (float*)(vtg + (size_t)4 * HDIM * TDIM); // [4*288][64][68]

    wtrans<<<768, 256, 0, stream>>>(Wk, Wq, Wv, wtg);
    qkv_proj<<<BT / 32, 512, 0, stream>>>(x, wtg, kg, qg, vtg);
    attn<<<4 * NSLOT, 256, 0, stream>>>(qg, kg, vtg, slabs);
    reduce_norm<<<BT * HDIM / (4 * 256), 256, 0, stream>>>(slabs, out);
}

// Round 7
// 138.368 us; speedup vs baseline: 1.0941x; 1.0239x over previous
//
#include <hip/hip_runtime.h>
#include <math.h>

// B=4, T=4096, C=1024, H=64. fp32 in/out, bf16 MFMA internally.
// K1 wtrans: W (C,H) fp32 -> WT bf16 [192][1024].
// K2 qkv_proj: 512 thr, K-step 64, [72]-short LDS rows, single-barrier dbuf,
//              8-deep x register ring (r6, unchanged).
// K3 attn: SOFTWARE-PIPELINED flash attention. Per iteration: stage(kt+1) ->
//          barrier -> QK(kt+1) MFMA -> PV(kt) MFMA (18 MFMA fused on the
//          matrix pipe) -> softmax(kt+1) on VALU/trans (its QK dependence is
//          hidden under PV) -> barrier. Only pa (8 VGPR) carried across iters.
//          Swapped mfma(K,Q); in-register P transpose via cvt_pk_bf16 +
//          permlane32/16_swap; l=sum(p) via register-constant ones fragment;
//          plain-store partials to private slab [slot][64][68].
// K4 reduce_norm: per row, sum ceil((qt+1)/8) slabs, out = O_sum / l_sum.

#define BT   16384
#define TDIM 4096
#define CDIM 1024
#define HDIM 64
#define ACCW 68           // slab row stride (floats); col 64 holds l
#define NSLOT 288         // chunk slots per batch (chunk = 8 kv-tiles)

typedef __attribute__((ext_vector_type(8))) short bf16x8;
typedef __attribute__((ext_vector_type(4))) float f32x4;
typedef __attribute__((ext_vector_type(8))) unsigned short us8;
typedef __attribute__((ext_vector_type(4))) unsigned short us4;

static __device__ __forceinline__ unsigned short f2bf(float f) {
    unsigned int u = __float_as_uint(f);
    u += 0x7fffu + ((u >> 16) & 1u);
    return (unsigned short)(u >> 16);
}

// Chained lane-swap: after pswap(x,y),
//   x = [X(q0), X(q2), Y(q0), Y(q2)] per quad, y = [X(q1), X(q3), Y(q1), Y(q3)]
// = A-frag words w / w+2 when X=c[st_lo][h], Y=c[st_hi][h].
static __device__ __forceinline__ void pswap(unsigned &x, unsigned &y) {
    asm("v_permlane32_swap_b32 %0, %1" : "+v"(x), "+v"(y));
    asm("v_permlane16_swap_b32 %0, %1" : "+v"(x), "+v"(y));
}

// p = exp(sT) (+ diagonal causal mask), packed into the PV A-fragment layout.
static __device__ __forceinline__ void softmax_pack(
    const f32x4 sT[4], bool diag, int qloc, int quad,
    bf16x8 &pa0, bf16x8 &pa1)
{
    float p[4][4];
    if (diag) {
        #pragma unroll
        for (int st = 0; st < 4; st++)
            #pragma unroll
            for (int r = 0; r < 4; r++) {
                int kkloc = st * 16 + quad * 4 + r;
                p[st][r] = (kkloc > qloc) ? 0.f : __expf(sT[st][r]);
            }
    } else {
        #pragma unroll
        for (int st = 0; st < 4; st++)
            #pragma unroll
            for (int r = 0; r < 4; r++)
                p[st][r] = __expf(sT[st][r]);
    }
    unsigned cpk[4][2];
    #pragma unroll
    for (int st = 0; st < 4; st++) {
        asm("v_cvt_pk_bf16_f32 %0, %1, %2"
            : "=v"(cpk[st][0]) : "v"(p[st][0]), "v"(p[st][1]));
        asm("v_cvt_pk_bf16_f32 %0, %1, %2"
            : "=v"(cpk[st][1]) : "v"(p[st][2]), "v"(p[st][3]));
    }
    union { unsigned u[4]; bf16x8 v; } u0, u1;
    unsigned a0 = cpk[0][0], b0 = cpk[1][0]; pswap(a0, b0);
    unsigned a1 = cpk[0][1], b1 = cpk[1][1]; pswap(a1, b1);
    u0.u[0] = a0; u0.u[1] = a1; u0.u[2] = b0; u0.u[3] = b1;
    unsigned a2 = cpk[2][0], b2 = cpk[3][0]; pswap(a2, b2);
    unsigned a3 = cpk[2][1], b3 = cpk[3][1]; pswap(a3, b3);
    u1.u[0] = a2; u1.u[1] = a3; u1.u[2] = b2; u1.u[3] = b3;
    pa0 = u0.v; pa1 = u1.v;
}

// ---------------- K1: W transpose->bf16 ----------------
__global__ __launch_bounds__(256) void wtrans(
    const float* __restrict__ Wk, const float* __restrict__ Wq,
    const float* __restrict__ Wv, unsigned short* __restrict__ wtg)
{
    int idx = blockIdx.x * 256 + threadIdx.x;     // 0..196607
    int mat = idx >> 16;
    int rem = idx & 65535;
    int h = rem >> 10, c = rem & 1023;
    const float* W = (mat == 0) ? Wk : (mat == 1) ? Wq : Wv;
    wtg[idx] = f2bf(W[c * HDIM + h]);             // WT[mat*64+h][c]
}

// ---------------- K2: QKV projection (8-deep x-ring, single-barrier dbuf) ---
__global__ __launch_bounds__(512) void qkv_proj(
    const float* __restrict__ x, const unsigned short* __restrict__ wtg,
    unsigned short* __restrict__ kg, unsigned short* __restrict__ qg,
    unsigned short* __restrict__ vtg)
{
    __shared__ __align__(16) unsigned short xs[2][32][72];
    __shared__ __align__(16) unsigned short wts[2][192][72];   // total 63 KB
    const int t = threadIdx.x;
    const int lane = t & 63, wv = t >> 6, quad = lane >> 4, l16 = lane & 15;
    const int mt = wv >> 2;                  // m-tile 0/1 (16 rows each)
    const int nq = wv & 3;                   // n-quarter: n-tiles nq*3..nq*3+2
    const int row0 = blockIdx.x * 32;

    const int xr = t >> 4, xc4 = (t & 15) * 4;       // x: 1 float4/thread/iter
    const int wn = t >> 3, wc8 = (t & 7) * 8;        // WT: 3 us8/thread/iter

    f32x4 acc3[3];
    #pragma unroll
    for (int i = 0; i < 3; i++) acc3[i] = (f32x4){0.f, 0.f, 0.f, 0.f};

    const size_t xrow = (size_t)(row0 + xr) * CDIM + xc4;

    // deep prefetch: issue 8 x-chunk loads up front (static-indexed ring)
    float4 xq[8];
    #pragma unroll
    for (int c = 0; c < 8; c++)
        xq[c] = *(const float4*)&x[xrow + c * 64];

    // WT chunk 0 regs
    us8 w0 = *(const us8*)&wtg[(size_t)(wn +   0) * CDIM + wc8];
    us8 w1 = *(const us8*)&wtg[(size_t)(wn +  64) * CDIM + wc8];
    us8 w2 = *(const us8*)&wtg[(size_t)(wn + 128) * CDIM + wc8];

    // stage tile 0 -> buf 0 (consumes xq[0]); refill slot 0 with chunk 8
    {
        us4 pk = { f2bf(xq[0].x), f2bf(xq[0].y), f2bf(xq[0].z), f2bf(xq[0].w) };
        *(us4*)&xs[0][xr][xc4] = pk;
        *(us8*)&wts[0][wn +   0][wc8] = w0;
        *(us8*)&wts[0][wn +  64][wc8] = w1;
        *(us8*)&wts[0][wn + 128][wc8] = w2;
    }
    xq[0] = *(const float4*)&x[xrow + 8 * 64];
    w0 = *(const us8*)&wtg[(size_t)(wn +   0) * CDIM + 64 + wc8];
    w1 = *(const us8*)&wtg[(size_t)(wn +  64) * CDIM + 64 + wc8];
    w2 = *(const us8*)&wtg[(size_t)(wn + 128) * CDIM + 64 + wc8];
    __syncthreads();

    #pragma unroll
    for (int it = 0; it < 16; it++) {
        const int buf = it & 1;
        if (it + 1 < 16) {
            // stage tile it+1 from ring slot (it+1)&7 and WT regs
            const int sl = (it + 1) & 7;
            us4 pk = { f2bf(xq[sl].x), f2bf(xq[sl].y),
                       f2bf(xq[sl].z), f2bf(xq[sl].w) };
            *(us4*)&xs[buf ^ 1][xr][xc4] = pk;
            *(us8*)&wts[buf ^ 1][wn +   0][wc8] = w0;
            *(us8*)&wts[buf ^ 1][wn +  64][wc8] = w1;
            *(us8*)&wts[buf ^ 1][wn + 128][wc8] = w2;
            if (it + 9 < 16)
                xq[sl] = *(const float4*)&x[xrow + (it + 9) * 64];
            if (it + 2 < 16) {
                int nc = (it + 2) * 64;
                w0 = *(const us8*)&wtg[(size_t)(wn +   0) * CDIM + nc + wc8];
                w1 = *(const us8*)&wtg[(size_t)(wn +  64) * CDIM + nc + wc8];
                w2 = *(const us8*)&wtg[(size_t)(wn + 128) * CDIM + nc + wc8];
            }
        }
        bf16x8 a0 = *(const bf16x8*)&xs[buf][mt * 16 + l16][quad * 8];
        bf16x8 a1 = *(const bf16x8*)&xs[buf][mt * 16 + l16][32 + quad * 8];
        #pragma unroll
        for (int j = 0; j < 3; j++) {
            int nt = nq * 3 + j;
            bf16x8 b0 = *(const bf16x8*)&wts[buf][nt * 16 + l16][quad * 8];
            bf16x8 b1 = *(const bf16x8*)&wts[buf][nt * 16 + l16][32 + quad * 8];
            acc3[j] = __builtin_amdgcn_mfma_f32_16x16x32_bf16(a0, b0, acc3[j], 0, 0, 0);
            acc3[j] = __builtin_amdgcn_mfma_f32_16x16x32_bf16(a1, b1, acc3[j], 0, 0, 0);
        }
        __syncthreads();
    }

    const int mrow = row0 + mt * 16 + quad * 4;
    #pragma unroll
    for (int j = 0; j < 3; j++) {
        int nt = nq * 3 + j;
        int mat = nt >> 2;
        int col = (nt & 3) * 16 + l16;
        if (mat == 2) {
            // V: 4 regs are 4 consecutive t at fixed h -> contiguous in vtg
            int bb = mrow >> 12, tr = mrow & 4095;   // rows never cross batch
            us4 pv = { f2bf(acc3[j][0]), f2bf(acc3[j][1]),
                       f2bf(acc3[j][2]), f2bf(acc3[j][3]) };
            *(us4*)&vtg[((size_t)(bb * HDIM + col) << 12) + tr] = pv;
        } else {
            // Q is pre-scaled by 1/8 (exact power-of-2 in bf16)
            float s = (mat == 1) ? 0.125f : 1.0f;
            unsigned short* dst = (mat == 0) ? kg : qg;
            #pragma unroll
            for (int reg = 0; reg < 4; reg++)
                dst[(size_t)(mrow + reg) * HDIM + col] = f2bf(acc3[j][reg] * s);
        }
    }
}

// ---------------- K3: software-pipelined flash attention ----------
// slot layout per batch (chunk = 8 tiles): group a = qt>>3 has (a+1) chunks
// per qt; group a starts at slot 4a(a+1); qt's slots: base + (qt&7)*(a+1).
__global__ __launch_bounds__(256) void attn(
    const unsigned short* __restrict__ qg, const unsigned short* __restrict__ kg,
    const unsigned short* __restrict__ vtg, float* __restrict__ slabs)
{
    __shared__ __align__(16) unsigned short Ks[2][64][72];
    __shared__ __align__(16) unsigned short Vt[2][64][72];    // 36 KB total

    const int t = threadIdx.x;
    const int lane = t & 63, wv = t >> 6, quad = lane >> 4, l16 = lane & 15;

    const int b = blockIdx.x / NSLOT;
    const int s = blockIdx.x - b * NSLOT;
    int a;
    if      (s < 8)   a = 0;
    else if (s < 24)  a = 1;
    else if (s < 48)  a = 2;
    else if (s < 80)  a = 3;
    else if (s < 120) a = 4;
    else if (s < 168) a = 5;
    else if (s < 224) a = 6;
    else              a = 7;
    const int u  = s - 4 * a * (a + 1);
    const int qt = a * 8 + u / (a + 1);
    const int c  = u % (a + 1);

    const size_t bbase = (size_t)b * TDIM;
    const int Q0 = qt * 64;
    const int kt0 = c * 8;
    const int kt1 = (kt0 + 7 < qt) ? kt0 + 7 : qt;

    // Q fragments (B-operand of swapped QK^T: n=l16 is the q-row)
    const int qrow = Q0 + wv * 16 + l16;
    const bf16x8 qa0 = *(const bf16x8*)&qg[(bbase + qrow) * HDIM + quad * 8];
    const bf16x8 qa1 = *(const bf16x8*)&qg[(bbase + qrow) * HDIM + 32 + quad * 8];

    // l-row B-fragment: register constant (col 0 of virtual ones-row)
    const short onev = (l16 == 0) ? (short)0x3F80 : (short)0;
    const bf16x8 ones = { onev, onev, onev, onev, onev, onev, onev, onev };

    f32x4 O[5];
    #pragma unroll
    for (int i = 0; i < 5; i++) O[i] = (f32x4){0.f, 0.f, 0.f, 0.f};

    const int fr = t >> 3, fc = (t & 7) * 8;

    // prologue: tile kt0 -> buf 0; preload tile kt0+1 into regs
    us8 kr0 = *(const us8*)&kg[(bbase + kt0 * 64 + fr) * HDIM + fc];
    us8 kr1 = *(const us8*)&kg[(bbase + kt0 * 64 + fr + 32) * HDIM + fc];
    us8 vr0 = *(const us8*)&vtg[((size_t)(b * HDIM + fr) << 12) + kt0 * 64 + fc];
    us8 vr1 = *(const us8*)&vtg[((size_t)(b * HDIM + fr + 32) << 12) + kt0 * 64 + fc];
    *(us8*)&Ks[0][fr][fc] = kr0;
    *(us8*)&Ks[0][fr + 32][fc] = kr1;
    *(us8*)&Vt[0][fr][fc] = vr0;
    *(us8*)&Vt[0][fr + 32][fc] = vr1;
    if (kt0 < kt1) {
        int kn = kt0 + 1;
        kr0 = *(const us8*)&kg[(bbase + kn * 64 + fr) * HDIM + fc];
        kr1 = *(const us8*)&kg[(bbase + kn * 64 + fr + 32) * HDIM + fc];
        vr0 = *(const us8*)&vtg[((size_t)(b * HDIM + fr) << 12) + kn * 64 + fc];
        vr1 = *(const us8*)&vtg[((size_t)(b * HDIM + fr + 32) << 12) + kn * 64 + fc];
    }
    __syncthreads();

    const int qloc = wv * 16 + l16;        // this lane's q row, Q-tile-local

    // prologue compute: QK(kt0) + softmax(kt0) -> pa
    bf16x8 pa0, pa1;
    {
        f32x4 sT[4];
        #pragma unroll
        for (int st = 0; st < 4; st++) {
            bf16x8 kb0 = *(const bf16x8*)&Ks[0][st * 16 + l16][quad * 8];
            bf16x8 kb1 = *(const bf16x8*)&Ks[0][st * 16 + l16][32 + quad * 8];
            f32x4 z = (f32x4){0.f, 0.f, 0.f, 0.f};
            z = __builtin_amdgcn_mfma_f32_16x16x32_bf16(kb0, qa0, z, 0, 0, 0);
            z = __builtin_amdgcn_mfma_f32_16x16x32_bf16(kb1, qa1, z, 0, 0, 0);
            sT[st] = z;
        }
        softmax_pack(sT, kt0 == qt, qloc, quad, pa0, pa1);
    }

    int buf = 0;
    for (int kt = kt0; kt < kt1; ++kt) {
        // stage tile kt+1 (in regs) into buf^1; issue preload of kt+2
        *(us8*)&Ks[buf ^ 1][fr][fc] = kr0;
        *(us8*)&Ks[buf ^ 1][fr + 32][fc] = kr1;
        *(us8*)&Vt[buf ^ 1][fr][fc] = vr0;
        *(us8*)&Vt[buf ^ 1][fr + 32][fc] = vr1;
        if (kt + 2 <= kt1) {
            int kn = kt + 2;
            kr0 = *(const us8*)&kg[(bbase + kn * 64 + fr) * HDIM + fc];
            kr1 = *(const us8*)&kg[(bbase + kn * 64 + fr + 32) * HDIM + fc];
            vr0 = *(const us8*)&vtg[((size_t)(b * HDIM + fr) << 12) + kn * 64 + fc];
            vr1 = *(const us8*)&vtg[((size_t)(b * HDIM + fr + 32) << 12) + kn * 64 + fc];
        }
        __syncthreads();

        // QK(kt+1) from Ks[buf^1], then PV(kt) from Vt[buf]: 18 MFMA fused.
        __builtin_amdgcn_s_setprio(1);
        f32x4 sT[4];
        #pragma unroll
        for (int st = 0; st < 4; st++) {
            bf16x8 kb0 = *(const bf16x8*)&Ks[buf ^ 1][st * 16 + l16][quad * 8];
            bf16x8 kb1 = *(const bf16x8*)&Ks[buf ^ 1][st * 16 + l16][32 + quad * 8];
            f32x4 z = (f32x4){0.f, 0.f, 0.f, 0.f};
            z = __builtin_amdgcn_mfma_f32_16x16x32_bf16(kb0, qa0, z, 0, 0, 0);
            z = __builtin_amdgcn_mfma_f32_16x16x32_bf16(kb1, qa1, z, 0, 0, 0);
            sT[st] = z;
        }
        #pragma unroll
        for (int nt = 0; nt < 4; nt++) {
            bf16x8 vb0 = *(const bf16x8*)&Vt[buf][nt * 16 + l16][quad * 8];
            bf16x8 vb1 = *(const bf16x8*)&Vt[buf][nt * 16 + l16][32 + quad * 8];
            O[nt] = __builtin_amdgcn_mfma_f32_16x16x32_bf16(pa0, vb0, O[nt], 0, 0, 0);
            O[nt] = __builtin_amdgcn_mfma_f32_16x16x32_bf16(pa1, vb1, O[nt], 0, 0, 0);
        }
        O[4] = __builtin_amdgcn_mfma_f32_16x16x32_bf16(pa0, ones, O[4], 0, 0, 0);
        O[4] = __builtin_amdgcn_mfma_f32_16x16x32_bf16(pa1, ones, O[4], 0, 0, 0);
        __builtin_amdgcn_s_setprio(0);

        // softmax(kt+1): its QK dependence drains while PV occupies the pipe
        softmax_pack(sT, (kt + 1) == qt, qloc, quad, pa0, pa1);

        __syncthreads();
        buf ^= 1;
    }

    // epilogue: PV(kt1) from Vt[buf]
    #pragma unroll
    for (int nt = 0; nt < 4; nt++) {
        bf16x8 vb0 = *(const bf16x8*)&Vt[buf][nt * 16 + l16][quad * 8];
        bf16x8 vb1 = *(const bf16x8*)&Vt[buf][nt * 16 + l16][32 + quad * 8];
        O[nt] = __builtin_amdgcn_mfma_f32_16x16x32_bf16(pa0, vb0, O[nt], 0, 0, 0);
        O[nt] = __builtin_amdgcn_mfma_f32_16x16x32_bf16(pa1, vb1, O[nt], 0, 0, 0);
    }
    O[4] = __builtin_amdgcn_mfma_f32_16x16x32_bf16(pa0, ones, O[4], 0, 0, 0);
    O[4] = __builtin_amdgcn_mfma_f32_16x16x32_bf16(pa1, ones, O[4], 0, 0, 0);

    // flush partials to this block's private slab slot (plain stores)
    float* slab = slabs + (size_t)(b * NSLOT + s) * 64 * ACCW;
    const int rl = wv * 16 + quad * 4;
    #pragma unroll
    for (int nt = 0; nt < 4; nt++)
        #pragma unroll
        for (int r = 0; r < 4; r++)
            slab[(size_t)(rl + r) * ACCW + nt * 16 + l16] = O[nt][r];
    if (l16 == 0) {
        #pragma unroll
        for (int r = 0; r < 4; r++)
            slab[(size_t)(rl + r) * ACCW + 64] = O[4][r];
    }
}

// ---------------- K4: reduce slabs + normalize ----------------
__global__ __launch_bounds__(256) void reduce_norm(
    const float* __restrict__ slabs, float* __restrict__ out)
{
    int idx = blockIdx.x * 256 + threadIdx.x;   // 262144 = 16384 rows * 16 float4
    int row = idx >> 4, c4 = (idx & 15) * 4;
    int b = row >> 12, qt = (row >> 6) & 63, r64 = row & 63;
    int a = qt >> 3, nc = a + 1;
    int base = 4 * a * (a + 1) + (qt & 7) * nc;    // first slot of this qt

    const float* sl = slabs + ((size_t)(b * NSLOT + base) * 64 + r64) * ACCW;
    float4 o = make_float4(0.f, 0.f, 0.f, 0.f);
    float l = 0.f;
    for (int i = 0; i < nc; i++) {
        float4 v = *(const float4*)&sl[c4];
        o.x += v.x; o.y += v.y; o.z += v.z; o.w += v.w;
        l += sl[64];
        sl += (size_t)64 * ACCW;
    }
    float inv = 1.f / l;
    *(float4*)&out[(size_t)row * HDIM + c4] =
        make_float4(o.x * inv, o.y * inv, o.z * inv, o.w * inv);
}

extern "C" void kernel_launch(void* const* d_in, const int* in_sizes, int n_in,
                              void* d_out, int out_size, void* d_ws, size_t ws_size,
                              hipStream_t stream) {
    const float* x  = (const float*)d_in[0];
    const float* Wk = (const float*)d_in[1];
    const float* Wq = (const float*)d_in[2];
    const float* Wv = (const float*)d_in[3];
    float* out = (float*)d_out;

    unsigned short* wtg = (unsigned short*)d_ws;        // [192][1024] bf16
    unsigned short* kg  = wtg + 196608;                 // [BT][64] bf16
    unsigned short* qg  = kg + (size_t)BT * HDIM;       // [BT][64] bf16 (q/8)
    unsigned short* vtg = qg + (size_t)BT * HDIM;       // [4][64][4096] bf16
    float* slabs = (float*)(vtg + (size_t)4 * HDIM * TDIM); // [4*288][64][68]

    wtrans<<<768, 256, 0, stream>>>(Wk, Wq, Wv, wtg);
    qkv_proj<<<BT / 32, 512, 0, stream>>>(x, wtg, kg, qg, vtg);
    attn<<<4 * NSLOT, 256, 0, stream>>>(qg, kg, vtg, slabs);
    reduce_norm<<<BT * HDIM / (4 * 256), 256, 0, stream>>>(slabs, out);
}